// Round 11
// baseline (894.066 us; speedup 1.0000x reference)
//
#include <hip/hip_runtime.h>
#include <hip/hip_fp16.h>
#include <math.h>

typedef unsigned short u16;
typedef unsigned int   u32;

// ---------------- dtype adaptivity (validated: inputs are f32/i32; keep as safety) ----
__device__ __forceinline__ bool is_f64(const void* amp){
  u32 u = ((const u32*)amp)[1];
  return ((u >> 20) & 0xFFF) >= 0x3FB;
}
__device__ __forceinline__ bool is_i64(const void* spos){
  const u32* p = (const u32*)spos;
  return (p[1] | p[3] | p[5]) == 0;
}
__device__ __forceinline__ float ldf(const void* p, size_t i, bool f64){
  return f64 ? (float)((const double*)p)[i] : ((const float*)p)[i];
}
__device__ __forceinline__ double lds_scalar(const void* p, bool f64){
  return f64 ? ((const double*)p)[0] : (double)((const float*)p)[0];
}
__device__ __forceinline__ int ldi(const void* p, size_t i, bool i64){
  return i64 ? (int)((const long long*)p)[i] : ((const int*)p)[i];
}

// ---------------- bf16 pack ----------------
__device__ __forceinline__ u16 f2bf(float f){
  u32 u = __float_as_uint(f);
  u32 r = 0x7fffu + ((u >> 16) & 1u);     // RNE
  return (u16)((u + r) >> 16);
}
// FINAL output store: pair order (im, re)
__device__ __forceinline__ void stout(void* p, size_t i, float2 v){
  ((u32*)p)[i] = (u32)f2bf(v.y) | ((u32)f2bf(v.x) << 16);
}

// ---------------- state accessors: H=1 -> fp16 (half2 per complex), H=0 -> fp32 ----
template<int H>
__device__ __forceinline__ float2 ld_state(const void* p, size_t i){
  if (H){
    __half2 h = ((const __half2*)p)[i];
    return __half22float2(h);
  }
  return ((const float2*)p)[i];
}
template<int H>
__device__ __forceinline__ void st_state(void* p, size_t i, float2 v){
  if (H) ((__half2*)p)[i] = __floats2half2_rn(v.x, v.y);
  else   ((float2*)p)[i] = v;
}

// ---------------- complex helpers ----------------
__device__ __forceinline__ float2 cadd(float2 a, float2 b){ return make_float2(a.x+b.x, a.y+b.y); }
__device__ __forceinline__ float2 csub(float2 a, float2 b){ return make_float2(a.x-b.x, a.y-b.y); }
__device__ __forceinline__ float2 cmul(float2 a, float2 b){ return make_float2(a.x*b.x - a.y*b.y, a.x*b.y + a.y*b.x); }
// multiply by conjugate of b
__device__ __forceinline__ float2 cmulc(float2 a, float2 b){ return make_float2(a.x*b.x + a.y*b.y, a.y*b.x - a.x*b.y); }
__device__ __forceinline__ float2 cscale(float2 a, float s){ return make_float2(a.x*s, a.y*s); }

template<int SGN>
__device__ __forceinline__ void fft4(float2& a, float2& b, float2& c, float2& d){
  float2 apc = cadd(a,c), amc = csub(a,c);
  float2 bpd = cadd(b,d), bmd = csub(b,d);
  float2 jb = (SGN < 0) ? make_float2(bmd.y, -bmd.x) : make_float2(-bmd.y, bmd.x);
  a = cadd(apc, bpd);
  b = cadd(amc, jb);
  c = csub(apc, bpd);
  d = csub(amc, jb);
}
template<int SGN>
__device__ __forceinline__ float2 twc(float2 z, float re, float im){
  float i2 = (SGN < 0) ? im : -im;
  return make_float2(z.x*re - z.y*i2, z.x*i2 + z.y*re);
}
template<int SGN>
__device__ __forceinline__ void fft16(float2 v[16]){
  float2 h[16];
#pragma unroll
  for (int n1=0;n1<4;n1++){
    float2 a=v[n1], b=v[n1+4], c=v[n1+8], d=v[n1+12];
    fft4<SGN>(a,b,c,d);
    h[n1*4+0]=a; h[n1*4+1]=b; h[n1*4+2]=c; h[n1*4+3]=d;
  }
  const float C1=0.92387953251f, S1=0.38268343236f, C2=0.70710678119f;
  h[5]  = twc<SGN>(h[5],  C1,-S1);
  h[6]  = twc<SGN>(h[6],  C2,-C2);
  h[7]  = twc<SGN>(h[7],  S1,-C1);
  h[9]  = twc<SGN>(h[9],  C2,-C2);
  h[10] = twc<SGN>(h[10], 0.f,-1.f);
  h[11] = twc<SGN>(h[11],-C2,-C2);
  h[13] = twc<SGN>(h[13], S1,-C1);
  h[14] = twc<SGN>(h[14],-C2,-C2);
  h[15] = twc<SGN>(h[15],-C1, S1);
#pragma unroll
  for (int q=0;q<4;q++){
    float2 a=h[q], b=h[4+q], c=h[8+q], d=h[12+q];
    fft4<SGN>(a,b,c,d);
    v[q]=a; v[q+4]=b; v[q+8]=c; v[q+12]=d;
  }
}

// ---------------- hoisted twiddles (REGISTERS -- r9 lesson: LDS table regressed,
// compiler hoists the loads back to regs anyway and adds latency) ----------------
// tw[q-1] = exp(-i*2pi*t*q/256). Both fft256 calls reuse it (SGN>0 via conjugate).
__device__ __forceinline__ void make_tw(float2 tw[15], int t){
  float s0, c0;
  sincosf(0.0245436926f * (float)t, &s0, &c0);   // 2*pi/256 * t
  float2 w1 = make_float2(c0, -s0);
  tw[0] = w1;
#pragma unroll
  for (int q=1;q<15;q++) tw[q] = cmul(tw[q-1], w1);
}

// ---------------- fft256 via LDS transpose, float2-packed buffer ----------------
// NEW (r11): single float2 T[4112] instead of split Tr/Ti float arrays. One
// ds_write_b64/ds_read_b64 per element instead of two b32 pairs: halves LDS
// instruction count (64->32 per fft256) AND the address VALU. Same fp32 values,
// same op order -> bit-identical results (absmax must stay 0.0625 exactly).
// b64 wave access = 512B = 4-cycle LDS minimum; XOR swizzle keeps per-bank load
// uniform (4 lanes/bank) -> no excess conflicts. Footprint unchanged (32.9KB).
// r6+r9: no fp16 packing (cvt tax). r7: BARRIER=0 for wave-private groups.
// r5: never force __launch_bounds__ min-waves (spill).
template<int SGN, int BARRIER>
__device__ __forceinline__ void fft256(float2 v[16], float2* T, int g, int t,
                                       const float2 tw[15]){
  fft16<SGN>(v);
#pragma unroll
  for (int q=1;q<16;q++){
    v[q] = (SGN < 0) ? cmul(v[q], tw[q-1]) : cmulc(v[q], tw[q-1]);
  }
  int base = g*257;
  if (BARRIER) __syncthreads();
#pragma unroll
  for (int k1=0;k1<16;k1++){
    int o = base + t*16 + (k1^t);
    T[o] = v[k1];
  }
  if (BARRIER) __syncthreads();
#pragma unroll
  for (int n1=0;n1<16;n1++){
    int o = base + n1*16 + (t^n1);
    v[n1] = T[o];
  }
  fft16<SGN>(v);
  if (SGN > 0){
#pragma unroll
    for (int q=0;q<16;q++) v[q] = cscale(v[q], 1.f/256.f);
  }
}

__device__ __forceinline__ float ffreq(int i){ return (float)(i < 128 ? i : i - 256) * 0.0390625f; }

#define LDS_F 4112
#define KMAX  1.26903553299f   // 0.025/0.0197
#define PHCONST 0.123778191f   // pi*lambda*dz = pi*0.0197*2.0

// ================== main path ==================
// d_out scratch: probe at +0 (512KB), ptmp at +512KB (overwritten by final pass).
// ws: state [B,256,256] half2; ttab (8x1024x1024 HALF2, 32 MB) after it.
// ttab fp16 (r10, proven): |T|~1, fp16 rel err 5e-4, absmax-neutral, -33MB/pass.
// H separable: col kernels build 256-entry h1 in LDS (r8, proven).

// ---------------- probe rows (wave-private FFT groups: no barriers) ----------------
__global__ void __launch_bounds__(256) probe_rowsF(const void* defocus, const void* Cs,
                                                   const void* astig_mag, const void* astig_angle,
                                                   const void* ap_smooth, const void* ampflag,
                                                   float2* tmp){
  __shared__ float2 T[LDS_F];
  bool f64 = is_f64(ampflag);
  int tid = threadIdx.x, g = tid>>4, t = tid&15;
  int r = blockIdx.x*16 + g;
  double df = lds_scalar(defocus, f64), cs = lds_scalar(Cs, f64);
  double am = lds_scalar(astig_mag, f64), aa = lds_scalar(astig_angle, f64);
  float sm = fabsf((float)lds_scalar(ap_smooth, f64)) + 0.01f;
  const double LAMd = 0.0197;
  float kxv = ffreq(r);
  float2 v[16];
#pragma unroll
  for (int j=0;j<16;j++){
    int c = t + 16*j;
    float kyv = ffreq(c);
    double k2 = (double)kxv*kxv + (double)kyv*kyv;
    float k  = sqrtf((float)k2);
    double ang = atan2((double)kyv, (double)kxv);
    double chi = M_PI*LAMd*df*k2
               + 0.5*M_PI*LAMd*LAMd*LAMd*(cs*1e6)*k2*k2
               + M_PI*LAMd*am*k2*cos(2.0*(ang - aa));
    float ap = 1.f/(1.f + expf(-(KMAX - k)/(KMAX*sm)));
    double sc = sin(chi), cc = cos(chi);
    v[j] = make_float2(ap*(float)cc, ap*(float)sc);
  }
  float2 tw[15]; make_tw(tw, t);
  fft256<1,0>(v, T, g, t, tw);
#pragma unroll
  for (int j=0;j<16;j++) tmp[(r<<8) + t + 16*j] = v[j];
}

// ---------------- probe cols (groups span waves: barriers required) -------------
__global__ void __launch_bounds__(256) probe_colsF(const float2* tmp, float2* probe_out,
                                                   const void* ap_smooth, const void* ampflag){
  __shared__ float2 T[LDS_F];
  __shared__ float Ssum[4];
  bool f64 = is_f64(ampflag);
  int tid = threadIdx.x, xl = tid&15, t = tid>>4;
  int cx = blockIdx.x*16 + xl;
  float sm = fabsf((float)lds_scalar(ap_smooth, f64)) + 0.01f;
  float S = 0.f;
  for (int i = tid; i < 65536; i += 256){
    float kx = ffreq(i>>8), ky = ffreq(i&255);
    float k = sqrtf(kx*kx + ky*ky);
    float ap = 1.f/(1.f + expf(-(KMAX - k)/(KMAX*sm)));
    S += ap*ap;
  }
#pragma unroll
  for (int off=32; off>0; off>>=1) S += __shfl_down(S, off);
  if ((tid&63)==0) Ssum[tid>>6] = S;
  __syncthreads();
  float scale = 256.f * rsqrtf(Ssum[0]+Ssum[1]+Ssum[2]+Ssum[3]);
  float2 v[16];
#pragma unroll
  for (int j=0;j<16;j++) v[j] = tmp[((t+16*j)<<8) + cx];
  float2 tw[15]; make_tw(tw, t);
  fft256<1,1>(v, T, xl, t, tw);
  int csh = (cx + 128) & 255;
#pragma unroll
  for (int j=0;j<16;j++){
    int y = t + 16*j;
    probe_out[(((y+128)&255)<<8) + csh] = cscale(v[j], scale);
  }
}

// ---------------- transmission table, fp16 (8x1024x1024 half2, 32 MB) ------------
__global__ void __launch_bounds__(256) build_ttabF(const void* amp, const void* phase,
                                                   __half2* ttab){
  bool f64 = is_f64(amp);
  int tid = threadIdx.x;
#pragma unroll
  for (int k=0;k<4;k++){
    size_t i = (size_t)blockIdx.x*1024 + tid + 256*k;
    float A = ldf(amp, i, f64);
    float P = ldf(phase, i, f64);
    float sp, cp; sincosf(P, &sp, &cp);
    ttab[i] = __floats2half2_rn(A*cp, A*sp);
  }
}

// ---------------- row pass: transmission PREFETCHED before FFT#1; NO barriers ----
template<int H>
__global__ void __launch_bounds__(256) row_passT(const void* amp, const void* phase,
                                                 const void* spos, const void* sidx,
                                                 void* state, const float2* probe,
                                                 const __half2* ttab, int s, int first,
                                                 int use_tt){
  __shared__ float2 T[LDS_F];
  bool f64 = is_f64(amp);
  bool i64 = is_i64(spos);
  int tid = threadIdx.x, g = tid>>4, t = tid&15;
  int b = blockIdx.y;
  int y = blockIdx.x*16 + g;
  int n = ldi(sidx, b, i64);
  int py = ldi(spos, 2*(size_t)n, i64), px = ldi(spos, 2*(size_t)n+1, i64);
  size_t rowbase = ((size_t)s<<20) + (size_t)(py+y)*1024 + px;
  float2 tv[16];
  if (use_tt){
#pragma unroll
    for (int j=0;j<16;j++) tv[j] = __half22float2(ttab[rowbase + t + 16*j]);
  } else {
#pragma unroll
    for (int j=0;j<16;j++){
      int x = t + 16*j;
      float A = ldf(amp,   rowbase + x, f64);
      float P = ldf(phase, rowbase + x, f64);
      float sp, cp; sincosf(P, &sp, &cp);
      tv[j] = make_float2(A*cp, A*sp);
    }
  }
  size_t ib = (size_t)b << 16;
  float2 tw[15]; make_tw(tw, t);
  float2 v[16];
  if (first){
#pragma unroll
    for (int j=0;j<16;j++) v[j] = probe[(y<<8) + t + 16*j];
  } else {
#pragma unroll
    for (int j=0;j<16;j++) v[j] = ld_state<H>(state, ib + (y<<8) + t + 16*j);
    fft256<1,0>(v, T, g, t, tw);
  }
#pragma unroll
  for (int j=0;j<16;j++) v[j] = cmul(v[j], tv[j]);
  fft256<-1,0>(v, T, g, t, tw);
#pragma unroll
  for (int j=0;j<16;j++) st_state<H>(state, ib + (y<<8) + t + 16*j, v[j]);
}

// ---------------- middle col pass: FFTc, xH (separable LDS h1), iFFTc ----------
template<int H>
__global__ void __launch_bounds__(256) col_passT(void* state){
  __shared__ float2 T[LDS_F];
  __shared__ float2 h1[256];
  int tid = threadIdx.x, xl = tid&15, t = tid>>4;
  int b = blockIdx.y;
  int cx = blockIdx.x*16 + xl;
  size_t ib = (size_t)b << 16;
  // fill h1: exp(i*PH*k^2) per 1D frequency (barrier inside fft256 covers the fill)
  {
    float kk = ffreq(tid);
    float a = PHCONST * kk * kk;
    float sa, ca; sincosf(a, &sa, &ca);
    h1[tid] = make_float2(ca, sa);
  }
  float2 tw[15]; make_tw(tw, t);
  float2 v[16];
#pragma unroll
  for (int j=0;j<16;j++) v[j] = ld_state<H>(state, ib + ((t+16*j)<<8) + cx);
  fft256<-1,1>(v, T, xl, t, tw);
  float2 hx = h1[cx & 255];
#pragma unroll
  for (int j=0;j<16;j++) v[j] = cmul(v[j], cmul(h1[t + 16*j], hx));
  fft256<1,1>(v, T, xl, t, tw);
#pragma unroll
  for (int j=0;j<16;j++) st_state<H>(state, ib + ((t+16*j)<<8) + cx, v[j]);
}

// ---------------- FINAL col pass: psi = fft2(exit7) * H ------------------------
// Algebraic fusion (r8, proven): psi = fft2(ifft2(fft2(exit7)*H)) = fft2(exit7)*H.
template<int H>
__global__ void __launch_bounds__(256) col_finT(void* state, void* outp){
  __shared__ float2 T[LDS_F];
  __shared__ float2 h1[256];
  int tid = threadIdx.x, xl = tid&15, t = tid>>4;
  int b = blockIdx.y;
  int cx = blockIdx.x*16 + xl;
  size_t ib = (size_t)b << 16;
  {
    float kk = ffreq(tid);
    float a = PHCONST * kk * kk;
    float sa, ca; sincosf(a, &sa, &ca);
    h1[tid] = make_float2(ca, sa);
  }
  float2 tw[15]; make_tw(tw, t);
  float2 v[16];
#pragma unroll
  for (int j=0;j<16;j++) v[j] = ld_state<H>(state, ib + ((t+16*j)<<8) + cx);
  fft256<-1,1>(v, T, xl, t, tw);
  float2 hx = h1[cx & 255];
#pragma unroll
  for (int j=0;j<16;j++){
    float2 r = cmul(v[j], cmul(h1[t + 16*j], hx));
    stout(outp, ib + ((t+16*j)<<8) + cx, r);
  }
}

template<int H>
static void run_new(const void* amp, const void* phase,
                    const void* df, const void* cs, const void* am, const void* aa,
                    const void* sm, const void* spos, const void* sidx, int B,
                    void* state, __half2* ttab, int use_tt,
                    void* dout, hipStream_t stream){
  char* dob = (char*)dout;
  float2* probe = (float2*)dob;
  float2* ptmp  = (float2*)(dob + 524288);
  probe_rowsF<<<16, 256, 0, stream>>>(df, cs, am, aa, sm, amp, ptmp);
  probe_colsF<<<16, 256, 0, stream>>>(ptmp, probe, sm, amp);
  if (use_tt) build_ttabF<<<8192, 256, 0, stream>>>(amp, phase, ttab);
  dim3 grid(16, B);
  row_passT<H><<<grid, 256, 0, stream>>>(amp, phase, spos, sidx, state, probe, ttab, 0, 1, use_tt);
  col_passT<H><<<grid, 256, 0, stream>>>(state);
  for (int s = 1; s < 7; s++){
    row_passT<H><<<grid, 256, 0, stream>>>(amp, phase, spos, sidx, state, probe, ttab, s, 0, use_tt);
    col_passT<H><<<grid, 256, 0, stream>>>(state);
  }
  row_passT<H><<<grid, 256, 0, stream>>>(amp, phase, spos, sidx, state, probe, ttab, 7, 0, use_tt);
  col_finT<H><<<grid, 256, 0, stream>>>(state, dout);
}

extern "C" void kernel_launch(void* const* d_in, const int* in_sizes, int n_in,
                              void* d_out, int out_size, void* d_ws, size_t ws_size,
                              hipStream_t stream) {
  const void* amp   = d_in[0];
  const void* phase = d_in[1];
  const void* df    = d_in[2];
  const void* cs    = d_in[3];
  const void* am    = d_in[4];
  const void* aa    = d_in[5];
  const void* sm    = d_in[6];
  const void* spos  = d_in[7];
  const void* sidx  = d_in[8];
  int B = in_sizes[8];
  (void)out_size; (void)n_in;

  size_t stateH = (size_t)B * 65536 * 4;            // fp16 state [B,256,256] c32 (half2)
  const size_t ttabB = (size_t)8 * 1024 * 1024 * 4; // 32 MB fp16 transmission table
  if (ws_size >= stateH + ttabB){
    void*    state = d_ws;
    __half2* ttab  = (__half2*)((char*)d_ws + stateH);
    run_new<1>(amp, phase, df, cs, am, aa, sm, spos, sidx, B,
               state, ttab, 1, d_out, stream);
  } else if (ws_size >= stateH){
    run_new<1>(amp, phase, df, cs, am, aa, sm, spos, sidx, B,
               d_ws, (__half2*)d_ws, 0, d_out, stream);
  } else {
    // no workspace: fp16 state lives in d_out itself (256KB/slot), tables inline
    run_new<1>(amp, phase, df, cs, am, aa, sm, spos, sidx, B,
               d_out, (__half2*)d_out, 0, d_out, stream);
  }
}

// Round 12
// 866.538 us; speedup vs baseline: 1.0318x; 1.0318x over previous
//
#include <hip/hip_runtime.h>
#include <hip/hip_fp16.h>
#include <math.h>

typedef unsigned short u16;
typedef unsigned int   u32;

// ---------------- dtype adaptivity (validated: inputs are f32/i32; keep as safety) ----
__device__ __forceinline__ bool is_f64(const void* amp){
  u32 u = ((const u32*)amp)[1];
  return ((u >> 20) & 0xFFF) >= 0x3FB;
}
__device__ __forceinline__ bool is_i64(const void* spos){
  const u32* p = (const u32*)spos;
  return (p[1] | p[3] | p[5]) == 0;
}
__device__ __forceinline__ float ldf(const void* p, size_t i, bool f64){
  return f64 ? (float)((const double*)p)[i] : ((const float*)p)[i];
}
__device__ __forceinline__ double lds_scalar(const void* p, bool f64){
  return f64 ? ((const double*)p)[0] : (double)((const float*)p)[0];
}
__device__ __forceinline__ int ldi(const void* p, size_t i, bool i64){
  return i64 ? (int)((const long long*)p)[i] : ((const int*)p)[i];
}

// ---------------- bf16 pack ----------------
__device__ __forceinline__ u16 f2bf(float f){
  u32 u = __float_as_uint(f);
  u32 r = 0x7fffu + ((u >> 16) & 1u);     // RNE
  return (u16)((u + r) >> 16);
}
// FINAL output store: pair order (im, re)
__device__ __forceinline__ void stout(void* p, size_t i, float2 v){
  ((u32*)p)[i] = (u32)f2bf(v.y) | ((u32)f2bf(v.x) << 16);
}

// ---------------- state accessors: H=1 -> fp16 (half2 per complex), H=0 -> fp32 ----
template<int H>
__device__ __forceinline__ float2 ld_state(const void* p, size_t i){
  if (H){
    __half2 h = ((const __half2*)p)[i];
    return __half22float2(h);
  }
  return ((const float2*)p)[i];
}
template<int H>
__device__ __forceinline__ void st_state(void* p, size_t i, float2 v){
  if (H) ((__half2*)p)[i] = __floats2half2_rn(v.x, v.y);
  else   ((float2*)p)[i] = v;
}

// ---------------- complex helpers ----------------
__device__ __forceinline__ float2 cadd(float2 a, float2 b){ return make_float2(a.x+b.x, a.y+b.y); }
__device__ __forceinline__ float2 csub(float2 a, float2 b){ return make_float2(a.x-b.x, a.y-b.y); }
__device__ __forceinline__ float2 cmul(float2 a, float2 b){ return make_float2(a.x*b.x - a.y*b.y, a.x*b.y + a.y*b.x); }
// multiply by conjugate of b
__device__ __forceinline__ float2 cmulc(float2 a, float2 b){ return make_float2(a.x*b.x + a.y*b.y, a.y*b.x - a.x*b.y); }
__device__ __forceinline__ float2 cscale(float2 a, float s){ return make_float2(a.x*s, a.y*s); }

template<int SGN>
__device__ __forceinline__ void fft4(float2& a, float2& b, float2& c, float2& d){
  float2 apc = cadd(a,c), amc = csub(a,c);
  float2 bpd = cadd(b,d), bmd = csub(b,d);
  float2 jb = (SGN < 0) ? make_float2(bmd.y, -bmd.x) : make_float2(-bmd.y, bmd.x);
  a = cadd(apc, bpd);
  b = cadd(amc, jb);
  c = csub(apc, bpd);
  d = csub(amc, jb);
}
template<int SGN>
__device__ __forceinline__ float2 twc(float2 z, float re, float im){
  float i2 = (SGN < 0) ? im : -im;
  return make_float2(z.x*re - z.y*i2, z.x*i2 + z.y*re);
}
template<int SGN>
__device__ __forceinline__ void fft16(float2 v[16]){
  float2 h[16];
#pragma unroll
  for (int n1=0;n1<4;n1++){
    float2 a=v[n1], b=v[n1+4], c=v[n1+8], d=v[n1+12];
    fft4<SGN>(a,b,c,d);
    h[n1*4+0]=a; h[n1*4+1]=b; h[n1*4+2]=c; h[n1*4+3]=d;
  }
  const float C1=0.92387953251f, S1=0.38268343236f, C2=0.70710678119f;
  h[5]  = twc<SGN>(h[5],  C1,-S1);
  h[6]  = twc<SGN>(h[6],  C2,-C2);
  h[7]  = twc<SGN>(h[7],  S1,-C1);
  h[9]  = twc<SGN>(h[9],  C2,-C2);
  h[10] = twc<SGN>(h[10], 0.f,-1.f);
  h[11] = twc<SGN>(h[11],-C2,-C2);
  h[13] = twc<SGN>(h[13], S1,-C1);
  h[14] = twc<SGN>(h[14],-C2,-C2);
  h[15] = twc<SGN>(h[15],-C1, S1);
#pragma unroll
  for (int q=0;q<4;q++){
    float2 a=h[q], b=h[4+q], c=h[8+q], d=h[12+q];
    fft4<SGN>(a,b,c,d);
    v[q]=a; v[q+4]=b; v[q+8]=c; v[q+12]=d;
  }
}

// ---------------- hoisted twiddles (REGISTERS -- r9: LDS table regressed) ---------
// tw[q-1] = exp(-i*2pi*t*q/256). Both fft256 calls reuse it (SGN>0 via conjugate).
__device__ __forceinline__ void make_tw(float2 tw[15], int t){
  float s0, c0;
  sincosf(0.0245436926f * (float)t, &s0, &c0);   // 2*pi/256 * t
  float2 w1 = make_float2(c0, -s0);
  tw[0] = w1;
#pragma unroll
  for (int q=1;q<15;q++) tw[q] = cmul(tw[q-1], w1);
}

// ---------------- fft256, split Tr/Ti b32 transpose (rows & probes) ----------------
// r11 lesson: b64-packed float2 T raised VGPR 72->100/116 (aligned-pair pressure),
// occupancy 23->16%, -10% perf. Split b32 Tr/Ti is REGISTER-optimal; keep it.
// r6+r9: no fp16 packing (cvt tax). r7: BARRIER=0 for wave-private groups.
// r5: never force __launch_bounds__ min-waves (spill).
template<int SGN, int BARRIER, int SCALE>
__device__ __forceinline__ void fft256(float2 v[16], float* Tr, float* Ti, int g, int t,
                                       const float2 tw[15]){
  fft16<SGN>(v);
#pragma unroll
  for (int q=1;q<16;q++){
    v[q] = (SGN < 0) ? cmul(v[q], tw[q-1]) : cmulc(v[q], tw[q-1]);
  }
  int base = g*257;
  if (BARRIER) __syncthreads();
#pragma unroll
  for (int k1=0;k1<16;k1++){
    int o = base + t*16 + (k1^t);
    Tr[o] = v[k1].x; Ti[o] = v[k1].y;
  }
  if (BARRIER) __syncthreads();
#pragma unroll
  for (int n1=0;n1<16;n1++){
    int o = base + n1*16 + (t^n1);
    v[n1] = make_float2(Tr[o], Ti[o]);
  }
  fft16<SGN>(v);
  if (SGN > 0 && SCALE){
#pragma unroll
    for (int q=0;q<16;q++) v[q] = cscale(v[q], 1.f/256.f);
  }
}

// ---------------- fft256s: sequential-reuse single T buffer (col family) -----------
// NEW (r12): ONE float T[4112] used twice -- Re round-trip then Im round-trip.
// Same op count & b32 widths as Tr/Ti (no VGPR delta: reads land directly in
// v[n].x / v[n].y), but halves col LDS 35.3->18.5KB -> block cap 4->8, wave cap
// 16->28/CU (VGPR=72 binds at 28). First cvt-free, VGPR-free occupancy-cap test.
// Cost: 4 barriers per fft256 instead of 2.
template<int SGN, int SCALE>
__device__ __forceinline__ void fft256s(float2 v[16], float* T, int g, int t,
                                        const float2 tw[15]){
  fft16<SGN>(v);
#pragma unroll
  for (int q=1;q<16;q++){
    v[q] = (SGN < 0) ? cmul(v[q], tw[q-1]) : cmulc(v[q], tw[q-1]);
  }
  int base = g*257;
  __syncthreads();
#pragma unroll
  for (int k1=0;k1<16;k1++) T[base + t*16 + (k1^t)] = v[k1].x;
  __syncthreads();
#pragma unroll
  for (int n1=0;n1<16;n1++) v[n1].x = T[base + n1*16 + (t^n1)];
  __syncthreads();
#pragma unroll
  for (int k1=0;k1<16;k1++) T[base + t*16 + (k1^t)] = v[k1].y;   // .y untouched above
  __syncthreads();
#pragma unroll
  for (int n1=0;n1<16;n1++) v[n1].y = T[base + n1*16 + (t^n1)];
  fft16<SGN>(v);
  if (SGN > 0 && SCALE){
#pragma unroll
    for (int q=0;q<16;q++) v[q] = cscale(v[q], 1.f/256.f);
  }
}

__device__ __forceinline__ float ffreq(int i){ return (float)(i < 128 ? i : i - 256) * 0.0390625f; }

#define LDS_F 4112
#define ISC   (1.f/256.f)
#define KMAX  1.26903553299f   // 0.025/0.0197
#define PHCONST 0.123778191f   // pi*lambda*dz = pi*0.0197*2.0

// ================== main path ==================
// Scale folding (r9 algebra, PASSED there at absmax 0.0625): ttab carries 1/256
// (row iFFT norm), mid-col h1 carries 1/16 per axis (h1y*h1x = H/256), probe
// carries x65536 (x256 old norm, x256 compensating ttab on first pass). Final
// col h1 unscaled. Each ifft2(s) gets 1/256 (col s) * 1/256 (row s+1) = 1/65536.
// d_out scratch: probe at +0 (512KB), ptmp at +512KB (final pass overwrites).
// ws: state [B,256,256] half2; ttab (8x1024x1024 HALF2, 32 MB) after it.

// ---------------- probe rows (wave-private FFT groups: no barriers) ----------------
__global__ void __launch_bounds__(256) probe_rowsF(const void* defocus, const void* Cs,
                                                   const void* astig_mag, const void* astig_angle,
                                                   const void* ap_smooth, const void* ampflag,
                                                   float2* tmp){
  __shared__ float Tr[LDS_F], Ti[LDS_F];
  bool f64 = is_f64(ampflag);
  int tid = threadIdx.x, g = tid>>4, t = tid&15;
  int r = blockIdx.x*16 + g;
  double df = lds_scalar(defocus, f64), cs = lds_scalar(Cs, f64);
  double am = lds_scalar(astig_mag, f64), aa = lds_scalar(astig_angle, f64);
  float sm = fabsf((float)lds_scalar(ap_smooth, f64)) + 0.01f;
  const double LAMd = 0.0197;
  float kxv = ffreq(r);
  float2 v[16];
#pragma unroll
  for (int j=0;j<16;j++){
    int c = t + 16*j;
    float kyv = ffreq(c);
    double k2 = (double)kxv*kxv + (double)kyv*kyv;
    float k  = sqrtf((float)k2);
    double ang = atan2((double)kyv, (double)kxv);
    double chi = M_PI*LAMd*df*k2
               + 0.5*M_PI*LAMd*LAMd*LAMd*(cs*1e6)*k2*k2
               + M_PI*LAMd*am*k2*cos(2.0*(ang - aa));
    float ap = 1.f/(1.f + expf(-(KMAX - k)/(KMAX*sm)));
    double sc = sin(chi), cc = cos(chi);
    v[j] = make_float2(ap*(float)cc, ap*(float)sc);
  }
  float2 tw[15]; make_tw(tw, t);
  fft256<1,0,1>(v, Tr, Ti, g, t, tw);
#pragma unroll
  for (int j=0;j<16;j++) tmp[(r<<8) + t + 16*j] = v[j];
}

// ---------------- probe cols (groups span waves: barriers required) -------------
__global__ void __launch_bounds__(256) probe_colsF(const float2* tmp, float2* probe_out,
                                                   const void* ap_smooth, const void* ampflag){
  __shared__ float Tr[LDS_F], Ti[LDS_F];
  __shared__ float Ssum[4];
  bool f64 = is_f64(ampflag);
  int tid = threadIdx.x, xl = tid&15, t = tid>>4;
  int cx = blockIdx.x*16 + xl;
  float sm = fabsf((float)lds_scalar(ap_smooth, f64)) + 0.01f;
  float S = 0.f;
  for (int i = tid; i < 65536; i += 256){
    float kx = ffreq(i>>8), ky = ffreq(i&255);
    float k = sqrtf(kx*kx + ky*ky);
    float ap = 1.f/(1.f + expf(-(KMAX - k)/(KMAX*sm)));
    S += ap*ap;
  }
#pragma unroll
  for (int off=32; off>0; off>>=1) S += __shfl_down(S, off);
  if ((tid&63)==0) Ssum[tid>>6] = S;
  __syncthreads();
  // x65536 = x256 (probe ifft2 norm via Parseval) * x256 (compensates ttab's
  // folded 1/256 on the first row pass -- probe is used only there)
  float scale = 65536.f * rsqrtf(Ssum[0]+Ssum[1]+Ssum[2]+Ssum[3]);
  float2 v[16];
#pragma unroll
  for (int j=0;j<16;j++) v[j] = tmp[((t+16*j)<<8) + cx];
  float2 tw[15]; make_tw(tw, t);
  fft256<1,1,1>(v, Tr, Ti, xl, t, tw);
  int csh = (cx + 128) & 255;
#pragma unroll
  for (int j=0;j<16;j++){
    int y = t + 16*j;
    probe_out[(((y+128)&255)<<8) + csh] = cscale(v[j], scale);
  }
}

// ---------------- transmission table, fp16, pre-scaled 1/256 ---------------------
__global__ void __launch_bounds__(256) build_ttabF(const void* amp, const void* phase,
                                                   __half2* ttab){
  bool f64 = is_f64(amp);
  int tid = threadIdx.x;
#pragma unroll
  for (int k=0;k<4;k++){
    size_t i = (size_t)blockIdx.x*1024 + tid + 256*k;
    float A = ldf(amp, i, f64);
    float P = ldf(phase, i, f64);
    float sp, cp; sincosf(P, &sp, &cp);
    ttab[i] = __floats2half2_rn(A*cp*ISC, A*sp*ISC);
  }
}

// ---------------- row pass: transmission PREFETCHED before FFT#1; NO barriers ----
template<int H>
__global__ void __launch_bounds__(256) row_passT(const void* amp, const void* phase,
                                                 const void* spos, const void* sidx,
                                                 void* state, const float2* probe,
                                                 const __half2* ttab, int s, int first,
                                                 int use_tt){
  __shared__ float Tr[LDS_F], Ti[LDS_F];
  bool f64 = is_f64(amp);
  bool i64 = is_i64(spos);
  int tid = threadIdx.x, g = tid>>4, t = tid&15;
  int b = blockIdx.y;
  int y = blockIdx.x*16 + g;
  int n = ldi(sidx, b, i64);
  int py = ldi(spos, 2*(size_t)n, i64), px = ldi(spos, 2*(size_t)n+1, i64);
  size_t rowbase = ((size_t)s<<20) + (size_t)(py+y)*1024 + px;
  float2 tv[16];
  if (use_tt){
#pragma unroll
    for (int j=0;j<16;j++) tv[j] = __half22float2(ttab[rowbase + t + 16*j]);
  } else {
#pragma unroll
    for (int j=0;j<16;j++){
      int x = t + 16*j;
      float A = ldf(amp,   rowbase + x, f64);
      float P = ldf(phase, rowbase + x, f64);
      float sp, cp; sincosf(P, &sp, &cp);
      tv[j] = make_float2(A*cp*ISC, A*sp*ISC);   // same 1/256 convention as ttab
    }
  }
  size_t ib = (size_t)b << 16;
  float2 tw[15]; make_tw(tw, t);
  float2 v[16];
  if (first){
#pragma unroll
    for (int j=0;j<16;j++) v[j] = probe[(y<<8) + t + 16*j];
  } else {
#pragma unroll
    for (int j=0;j<16;j++) v[j] = ld_state<H>(state, ib + (y<<8) + t + 16*j);
    fft256<1,0,0>(v, Tr, Ti, g, t, tw);     // iFFT scale folded into ttab
  }
#pragma unroll
  for (int j=0;j<16;j++) v[j] = cmul(v[j], tv[j]);
  fft256<-1,0,0>(v, Tr, Ti, g, t, tw);
#pragma unroll
  for (int j=0;j<16;j++) st_state<H>(state, ib + (y<<8) + t + 16*j, v[j]);
}

// ---------------- middle col pass: FFTc, xH (h1 pre-scaled 1/16), iFFTc ----------
template<int H>
__global__ void __launch_bounds__(256) col_passT(void* state){
  __shared__ float T[LDS_F];
  __shared__ float2 h1[256];
  int tid = threadIdx.x, xl = tid&15, t = tid>>4;
  int b = blockIdx.y;
  int cx = blockIdx.x*16 + xl;
  size_t ib = (size_t)b << 16;
  // fill h1 (first barrier inside fft256s covers visibility)
  {
    float kk = ffreq(tid);
    float a = PHCONST * kk * kk;
    float sa, ca; sincosf(a, &sa, &ca);
    h1[tid] = make_float2(ca*0.0625f, sa*0.0625f);   // 1/16 per axis -> H/256
  }
  float2 tw[15]; make_tw(tw, t);
  float2 v[16];
#pragma unroll
  for (int j=0;j<16;j++) v[j] = ld_state<H>(state, ib + ((t+16*j)<<8) + cx);
  fft256s<-1,0>(v, T, xl, t, tw);
  float2 hx = h1[cx & 255];
#pragma unroll
  for (int j=0;j<16;j++) v[j] = cmul(v[j], cmul(h1[t + 16*j], hx));
  fft256s<1,0>(v, T, xl, t, tw);            // iFFT scale folded into h1
#pragma unroll
  for (int j=0;j<16;j++) st_state<H>(state, ib + ((t+16*j)<<8) + cx, v[j]);
}

// ---------------- FINAL col pass: psi = fft2(exit7) * H (h1 unscaled) ----------
// Algebraic fusion (r8, proven): psi = fft2(ifft2(fft2(exit7)*H)) = fft2(exit7)*H.
template<int H>
__global__ void __launch_bounds__(256) col_finT(void* state, void* outp){
  __shared__ float T[LDS_F];
  __shared__ float2 h1[256];
  int tid = threadIdx.x, xl = tid&15, t = tid>>4;
  int b = blockIdx.y;
  int cx = blockIdx.x*16 + xl;
  size_t ib = (size_t)b << 16;
  {
    float kk = ffreq(tid);
    float a = PHCONST * kk * kk;
    float sa, ca; sincosf(a, &sa, &ca);
    h1[tid] = make_float2(ca, sa);
  }
  float2 tw[15]; make_tw(tw, t);
  float2 v[16];
#pragma unroll
  for (int j=0;j<16;j++) v[j] = ld_state<H>(state, ib + ((t+16*j)<<8) + cx);
  fft256s<-1,0>(v, T, xl, t, tw);
  float2 hx = h1[cx & 255];
#pragma unroll
  for (int j=0;j<16;j++){
    float2 r = cmul(v[j], cmul(h1[t + 16*j], hx));
    stout(outp, ib + ((t+16*j)<<8) + cx, r);
  }
}

template<int H>
static void run_new(const void* amp, const void* phase,
                    const void* df, const void* cs, const void* am, const void* aa,
                    const void* sm, const void* spos, const void* sidx, int B,
                    void* state, __half2* ttab, int use_tt,
                    void* dout, hipStream_t stream){
  char* dob = (char*)dout;
  float2* probe = (float2*)dob;
  float2* ptmp  = (float2*)(dob + 524288);
  probe_rowsF<<<16, 256, 0, stream>>>(df, cs, am, aa, sm, amp, ptmp);
  probe_colsF<<<16, 256, 0, stream>>>(ptmp, probe, sm, amp);
  if (use_tt) build_ttabF<<<8192, 256, 0, stream>>>(amp, phase, ttab);
  dim3 grid(16, B);
  row_passT<H><<<grid, 256, 0, stream>>>(amp, phase, spos, sidx, state, probe, ttab, 0, 1, use_tt);
  col_passT<H><<<grid, 256, 0, stream>>>(state);
  for (int s = 1; s < 7; s++){
    row_passT<H><<<grid, 256, 0, stream>>>(amp, phase, spos, sidx, state, probe, ttab, s, 0, use_tt);
    col_passT<H><<<grid, 256, 0, stream>>>(state);
  }
  row_passT<H><<<grid, 256, 0, stream>>>(amp, phase, spos, sidx, state, probe, ttab, 7, 0, use_tt);
  col_finT<H><<<grid, 256, 0, stream>>>(state, dout);
}

extern "C" void kernel_launch(void* const* d_in, const int* in_sizes, int n_in,
                              void* d_out, int out_size, void* d_ws, size_t ws_size,
                              hipStream_t stream) {
  const void* amp   = d_in[0];
  const void* phase = d_in[1];
  const void* df    = d_in[2];
  const void* cs    = d_in[3];
  const void* am    = d_in[4];
  const void* aa    = d_in[5];
  const void* sm    = d_in[6];
  const void* spos  = d_in[7];
  const void* sidx  = d_in[8];
  int B = in_sizes[8];
  (void)out_size; (void)n_in;

  size_t stateH = (size_t)B * 65536 * 4;            // fp16 state [B,256,256] c32 (half2)
  const size_t ttabB = (size_t)8 * 1024 * 1024 * 4; // 32 MB fp16 transmission table
  if (ws_size >= stateH + ttabB){
    void*    state = d_ws;
    __half2* ttab  = (__half2*)((char*)d_ws + stateH);
    run_new<1>(amp, phase, df, cs, am, aa, sm, spos, sidx, B,
               state, ttab, 1, d_out, stream);
  } else if (ws_size >= stateH){
    run_new<1>(amp, phase, df, cs, am, aa, sm, spos, sidx, B,
               d_ws, (__half2*)d_ws, 0, d_out, stream);
  } else {
    // no workspace: fp16 state lives in d_out itself (256KB/slot), tables inline
    run_new<1>(amp, phase, df, cs, am, aa, sm, spos, sidx, B,
               d_out, (__half2*)d_out, 0, d_out, stream);
  }
}

// Round 13
// 803.121 us; speedup vs baseline: 1.1132x; 1.0790x over previous
//
#include <hip/hip_runtime.h>
#include <hip/hip_fp16.h>
#include <math.h>

typedef unsigned short u16;
typedef unsigned int   u32;

// ---------------- dtype adaptivity (validated: inputs are f32/i32; keep as safety) ----
__device__ __forceinline__ bool is_f64(const void* amp){
  u32 u = ((const u32*)amp)[1];
  return ((u >> 20) & 0xFFF) >= 0x3FB;
}
__device__ __forceinline__ bool is_i64(const void* spos){
  const u32* p = (const u32*)spos;
  return (p[1] | p[3] | p[5]) == 0;
}
__device__ __forceinline__ float ldf(const void* p, size_t i, bool f64){
  return f64 ? (float)((const double*)p)[i] : ((const float*)p)[i];
}
__device__ __forceinline__ double lds_scalar(const void* p, bool f64){
  return f64 ? ((const double*)p)[0] : (double)((const float*)p)[0];
}
__device__ __forceinline__ int ldi(const void* p, size_t i, bool i64){
  return i64 ? (int)((const long long*)p)[i] : ((const int*)p)[i];
}

// ---------------- bf16 pack ----------------
__device__ __forceinline__ u16 f2bf(float f){
  u32 u = __float_as_uint(f);
  u32 r = 0x7fffu + ((u >> 16) & 1u);     // RNE
  return (u16)((u + r) >> 16);
}
// FINAL output store: pair order (im, re)
__device__ __forceinline__ void stout(void* p, size_t i, float2 v){
  ((u32*)p)[i] = (u32)f2bf(v.y) | ((u32)f2bf(v.x) << 16);
}

// ---------------- state accessors: H=1 -> fp16 (half2 per complex), H=0 -> fp32 ----
template<int H>
__device__ __forceinline__ float2 ld_state(const void* p, size_t i){
  if (H){
    __half2 h = ((const __half2*)p)[i];
    return __half22float2(h);
  }
  return ((const float2*)p)[i];
}
template<int H>
__device__ __forceinline__ void st_state(void* p, size_t i, float2 v){
  if (H) ((__half2*)p)[i] = __floats2half2_rn(v.x, v.y);
  else   ((float2*)p)[i] = v;
}

// ---------------- complex helpers ----------------
__device__ __forceinline__ float2 cadd(float2 a, float2 b){ return make_float2(a.x+b.x, a.y+b.y); }
__device__ __forceinline__ float2 csub(float2 a, float2 b){ return make_float2(a.x-b.x, a.y-b.y); }
__device__ __forceinline__ float2 cmul(float2 a, float2 b){ return make_float2(a.x*b.x - a.y*b.y, a.x*b.y + a.y*b.x); }
// multiply by conjugate of b
__device__ __forceinline__ float2 cmulc(float2 a, float2 b){ return make_float2(a.x*b.x + a.y*b.y, a.y*b.x - a.x*b.y); }
__device__ __forceinline__ float2 cscale(float2 a, float s){ return make_float2(a.x*s, a.y*s); }

template<int SGN>
__device__ __forceinline__ void fft4(float2& a, float2& b, float2& c, float2& d){
  float2 apc = cadd(a,c), amc = csub(a,c);
  float2 bpd = cadd(b,d), bmd = csub(b,d);
  float2 jb = (SGN < 0) ? make_float2(bmd.y, -bmd.x) : make_float2(-bmd.y, bmd.x);
  a = cadd(apc, bpd);
  b = cadd(amc, jb);
  c = csub(apc, bpd);
  d = csub(amc, jb);
}
template<int SGN>
__device__ __forceinline__ float2 twc(float2 z, float re, float im){
  float i2 = (SGN < 0) ? im : -im;
  return make_float2(z.x*re - z.y*i2, z.x*i2 + z.y*re);
}
template<int SGN>
__device__ __forceinline__ void fft16(float2 v[16]){
  float2 h[16];
#pragma unroll
  for (int n1=0;n1<4;n1++){
    float2 a=v[n1], b=v[n1+4], c=v[n1+8], d=v[n1+12];
    fft4<SGN>(a,b,c,d);
    h[n1*4+0]=a; h[n1*4+1]=b; h[n1*4+2]=c; h[n1*4+3]=d;
  }
  const float C1=0.92387953251f, S1=0.38268343236f, C2=0.70710678119f;
  h[5]  = twc<SGN>(h[5],  C1,-S1);
  h[6]  = twc<SGN>(h[6],  C2,-C2);
  h[7]  = twc<SGN>(h[7],  S1,-C1);
  h[9]  = twc<SGN>(h[9],  C2,-C2);
  h[10] = twc<SGN>(h[10], 0.f,-1.f);
  h[11] = twc<SGN>(h[11],-C2,-C2);
  h[13] = twc<SGN>(h[13], S1,-C1);
  h[14] = twc<SGN>(h[14],-C2,-C2);
  h[15] = twc<SGN>(h[15],-C1, S1);
#pragma unroll
  for (int q=0;q<4;q++){
    float2 a=h[q], b=h[4+q], c=h[8+q], d=h[12+q];
    fft4<SGN>(a,b,c,d);
    v[q]=a; v[q+4]=b; v[q+8]=c; v[q+12]=d;
  }
}

// ---------------- hoisted twiddles (REGISTERS -- r9: LDS table regressed) ---------
// tw[q-1] = exp(-i*2pi*t*q/256). Both fft256 calls reuse it (SGN>0 via conjugate).
__device__ __forceinline__ void make_tw(float2 tw[15], int t){
  float s0, c0;
  sincosf(0.0245436926f * (float)t, &s0, &c0);   // 2*pi/256 * t
  float2 w1 = make_float2(c0, -s0);
  tw[0] = w1;
#pragma unroll
  for (int q=1;q<15;q++) tw[q] = cmul(tw[q-1], w1);
}

// ---------------- fft256, split Tr/Ti b32 transpose (col family) ----------------
// Ledger: r11 b64 float2 T -> VGPR 100/116 (aligned-pair pressure), -10%. r6/r9
// fp16-packed LDS -> cvt tax, -5..11%. r12 scale folding -> rows -10% (unexplained
// codegen; reverted). r5: never force __launch_bounds__ min-waves (spill).
// This split-b32 form with SCALE in the inverse FFT is the measured-best (r10, 813us).
template<int SGN, int BARRIER>
__device__ __forceinline__ void fft256(float2 v[16], float* Tr, float* Ti, int g, int t,
                                       const float2 tw[15]){
  fft16<SGN>(v);
#pragma unroll
  for (int q=1;q<16;q++){
    v[q] = (SGN < 0) ? cmul(v[q], tw[q-1]) : cmulc(v[q], tw[q-1]);
  }
  int base = g*257;
  if (BARRIER) __syncthreads();
#pragma unroll
  for (int k1=0;k1<16;k1++){
    int o = base + t*16 + (k1^t);
    Tr[o] = v[k1].x; Ti[o] = v[k1].y;
  }
  if (BARRIER) __syncthreads();
#pragma unroll
  for (int n1=0;n1<16;n1++){
    int o = base + n1*16 + (t^n1);
    v[n1] = make_float2(Tr[o], Ti[o]);
  }
  fft16<SGN>(v);
  if (SGN > 0){
#pragma unroll
    for (int q=0;q<16;q++) v[q] = cscale(v[q], 1.f/256.f);
  }
}

// ---------------- fft256r: sequential-reuse single-T transpose, ROW family --------
// NEW (r13): one float T[4112] used twice (Re round-trip, then Im). Row FFT groups
// are WAVE-PRIVATE (g=tid>>4, region g*257) -> NO barriers needed even with the
// sequential reuse: in-wave LDS ordering (compiler lgkmcnt) covers the WAR on T.
// Zero cvts, zero VGPR delta (reads land in v[n].x/.y directly), same op count;
// row LDS 33.3->16.6KB lifts the block cap 4->5 (VGPR 88 binds at 5 blocks/CU,
// 20 waves vs 16). Bit-identical math to r10's fft256.
template<int SGN>
__device__ __forceinline__ void fft256r(float2 v[16], float* T, int g, int t,
                                        const float2 tw[15]){
  fft16<SGN>(v);
#pragma unroll
  for (int q=1;q<16;q++){
    v[q] = (SGN < 0) ? cmul(v[q], tw[q-1]) : cmulc(v[q], tw[q-1]);
  }
  int base = g*257;
#pragma unroll
  for (int k1=0;k1<16;k1++) T[base + t*16 + (k1^t)] = v[k1].x;
#pragma unroll
  for (int n1=0;n1<16;n1++) v[n1].x = T[base + n1*16 + (t^n1)];
#pragma unroll
  for (int k1=0;k1<16;k1++) T[base + t*16 + (k1^t)] = v[k1].y;
#pragma unroll
  for (int n1=0;n1<16;n1++) v[n1].y = T[base + n1*16 + (t^n1)];
  fft16<SGN>(v);
  if (SGN > 0){
#pragma unroll
    for (int q=0;q<16;q++) v[q] = cscale(v[q], 1.f/256.f);
  }
}

__device__ __forceinline__ float ffreq(int i){ return (float)(i < 128 ? i : i - 256) * 0.0390625f; }

#define LDS_F 4112
#define KMAX  1.26903553299f   // 0.025/0.0197
#define PHCONST 0.123778191f   // pi*lambda*dz = pi*0.0197*2.0

// ================== main path (r10 structure, proven 813us) ==================
// d_out scratch: probe at +0 (512KB), ptmp at +512KB (overwritten by final pass).
// ws: state [B,256,256] half2; ttab (8x1024x1024 HALF2, 32 MB) after it.
// ttab fp16 (r10, proven): |T|~1, fp16 rel err 5e-4, absmax-neutral, -33MB/pass.
// H separable: col kernels build 256-entry h1 in LDS (r8, proven). NO scale
// folding (r12 lesson).

// ---------------- probe rows (wave-private FFT groups: no barriers, seq-T) -------
__global__ void __launch_bounds__(256) probe_rowsF(const void* defocus, const void* Cs,
                                                   const void* astig_mag, const void* astig_angle,
                                                   const void* ap_smooth, const void* ampflag,
                                                   float2* tmp){
  __shared__ float T[LDS_F];
  bool f64 = is_f64(ampflag);
  int tid = threadIdx.x, g = tid>>4, t = tid&15;
  int r = blockIdx.x*16 + g;
  double df = lds_scalar(defocus, f64), cs = lds_scalar(Cs, f64);
  double am = lds_scalar(astig_mag, f64), aa = lds_scalar(astig_angle, f64);
  float sm = fabsf((float)lds_scalar(ap_smooth, f64)) + 0.01f;
  const double LAMd = 0.0197;
  float kxv = ffreq(r);
  float2 v[16];
#pragma unroll
  for (int j=0;j<16;j++){
    int c = t + 16*j;
    float kyv = ffreq(c);
    double k2 = (double)kxv*kxv + (double)kyv*kyv;
    float k  = sqrtf((float)k2);
    double ang = atan2((double)kyv, (double)kxv);
    double chi = M_PI*LAMd*df*k2
               + 0.5*M_PI*LAMd*LAMd*LAMd*(cs*1e6)*k2*k2
               + M_PI*LAMd*am*k2*cos(2.0*(ang - aa));
    float ap = 1.f/(1.f + expf(-(KMAX - k)/(KMAX*sm)));
    double sc = sin(chi), cc = cos(chi);
    v[j] = make_float2(ap*(float)cc, ap*(float)sc);
  }
  float2 tw[15]; make_tw(tw, t);
  fft256r<1>(v, T, g, t, tw);
#pragma unroll
  for (int j=0;j<16;j++) tmp[(r<<8) + t + 16*j] = v[j];
}

// ---------------- probe cols (groups span waves: barriers required) -------------
__global__ void __launch_bounds__(256) probe_colsF(const float2* tmp, float2* probe_out,
                                                   const void* ap_smooth, const void* ampflag){
  __shared__ float Tr[LDS_F], Ti[LDS_F];
  bool f64 = is_f64(ampflag);
  int tid = threadIdx.x, xl = tid&15, t = tid>>4;
  int cx = blockIdx.x*16 + xl;
  float sm = fabsf((float)lds_scalar(ap_smooth, f64)) + 0.01f;
  float S = 0.f;
  for (int i = tid; i < 65536; i += 256){
    float kx = ffreq(i>>8), ky = ffreq(i&255);
    float k = sqrtf(kx*kx + ky*ky);
    float ap = 1.f/(1.f + expf(-(KMAX - k)/(KMAX*sm)));
    S += ap*ap;
  }
#pragma unroll
  for (int off=32; off>0; off>>=1) S += __shfl_down(S, off);
  if ((tid&63)==0) Tr[tid>>6] = S;
  __syncthreads();
  float scale = 256.f * rsqrtf(Tr[0]+Tr[1]+Tr[2]+Tr[3]);
  float2 v[16];
#pragma unroll
  for (int j=0;j<16;j++) v[j] = tmp[((t+16*j)<<8) + cx];
  float2 tw[15]; make_tw(tw, t);
  fft256<1,1>(v, Tr, Ti, xl, t, tw);
  int csh = (cx + 128) & 255;
#pragma unroll
  for (int j=0;j<16;j++){
    int y = t + 16*j;
    probe_out[(((y+128)&255)<<8) + csh] = cscale(v[j], scale);
  }
}

// ---------------- transmission table, fp16 (8x1024x1024 half2, 32 MB) ------------
__global__ void __launch_bounds__(256) build_ttabF(const void* amp, const void* phase,
                                                   __half2* ttab){
  bool f64 = is_f64(amp);
  int tid = threadIdx.x;
#pragma unroll
  for (int k=0;k<4;k++){
    size_t i = (size_t)blockIdx.x*1024 + tid + 256*k;
    float A = ldf(amp, i, f64);
    float P = ldf(phase, i, f64);
    float sp, cp; sincosf(P, &sp, &cp);
    ttab[i] = __floats2half2_rn(A*cp, A*sp);
  }
}

// ---------------- row pass: T prefetch before FFT#1; NO barriers; seq-T ----------
template<int H>
__global__ void __launch_bounds__(256) row_passT(const void* amp, const void* phase,
                                                 const void* spos, const void* sidx,
                                                 void* state, const float2* probe,
                                                 const __half2* ttab, int s, int first,
                                                 int use_tt){
  __shared__ float T[LDS_F];
  bool f64 = is_f64(amp);
  bool i64 = is_i64(spos);
  int tid = threadIdx.x, g = tid>>4, t = tid&15;
  int b = blockIdx.y;
  int y = blockIdx.x*16 + g;
  int n = ldi(sidx, b, i64);
  int py = ldi(spos, 2*(size_t)n, i64), px = ldi(spos, 2*(size_t)n+1, i64);
  size_t rowbase = ((size_t)s<<20) + (size_t)(py+y)*1024 + px;
  float2 tv[16];
  if (use_tt){
#pragma unroll
    for (int j=0;j<16;j++) tv[j] = __half22float2(ttab[rowbase + t + 16*j]);
  } else {
#pragma unroll
    for (int j=0;j<16;j++){
      int x = t + 16*j;
      float A = ldf(amp,   rowbase + x, f64);
      float P = ldf(phase, rowbase + x, f64);
      float sp, cp; sincosf(P, &sp, &cp);
      tv[j] = make_float2(A*cp, A*sp);
    }
  }
  size_t ib = (size_t)b << 16;
  float2 tw[15]; make_tw(tw, t);
  float2 v[16];
  if (first){
#pragma unroll
    for (int j=0;j<16;j++) v[j] = probe[(y<<8) + t + 16*j];
  } else {
#pragma unroll
    for (int j=0;j<16;j++) v[j] = ld_state<H>(state, ib + (y<<8) + t + 16*j);
    fft256r<1>(v, T, g, t, tw);
  }
#pragma unroll
  for (int j=0;j<16;j++) v[j] = cmul(v[j], tv[j]);
  fft256r<-1>(v, T, g, t, tw);
#pragma unroll
  for (int j=0;j<16;j++) st_state<H>(state, ib + (y<<8) + t + 16*j, v[j]);
}

// ---------------- middle col pass: FFTc, xH (separable LDS h1), iFFTc ----------
template<int H>
__global__ void __launch_bounds__(256) col_passT(void* state){
  __shared__ float Tr[LDS_F], Ti[LDS_F];
  __shared__ float2 h1[256];
  int tid = threadIdx.x, xl = tid&15, t = tid>>4;
  int b = blockIdx.y;
  int cx = blockIdx.x*16 + xl;
  size_t ib = (size_t)b << 16;
  // fill h1: exp(i*PH*k^2) per 1D frequency (barrier inside fft256 covers the fill)
  {
    float kk = ffreq(tid);
    float a = PHCONST * kk * kk;
    float sa, ca; sincosf(a, &sa, &ca);
    h1[tid] = make_float2(ca, sa);
  }
  float2 tw[15]; make_tw(tw, t);
  float2 v[16];
#pragma unroll
  for (int j=0;j<16;j++) v[j] = ld_state<H>(state, ib + ((t+16*j)<<8) + cx);
  fft256<-1,1>(v, Tr, Ti, xl, t, tw);
  float2 hx = h1[cx & 255];
#pragma unroll
  for (int j=0;j<16;j++) v[j] = cmul(v[j], cmul(h1[t + 16*j], hx));
  fft256<1,1>(v, Tr, Ti, xl, t, tw);
#pragma unroll
  for (int j=0;j<16;j++) st_state<H>(state, ib + ((t+16*j)<<8) + cx, v[j]);
}

// ---------------- FINAL col pass: psi = fft2(exit7) * H ------------------------
// Algebraic fusion (r8, proven): psi = fft2(ifft2(fft2(exit7)*H)) = fft2(exit7)*H.
template<int H>
__global__ void __launch_bounds__(256) col_finT(void* state, void* outp){
  __shared__ float Tr[LDS_F], Ti[LDS_F];
  __shared__ float2 h1[256];
  int tid = threadIdx.x, xl = tid&15, t = tid>>4;
  int b = blockIdx.y;
  int cx = blockIdx.x*16 + xl;
  size_t ib = (size_t)b << 16;
  {
    float kk = ffreq(tid);
    float a = PHCONST * kk * kk;
    float sa, ca; sincosf(a, &sa, &ca);
    h1[tid] = make_float2(ca, sa);
  }
  float2 tw[15]; make_tw(tw, t);
  float2 v[16];
#pragma unroll
  for (int j=0;j<16;j++) v[j] = ld_state<H>(state, ib + ((t+16*j)<<8) + cx);
  fft256<-1,1>(v, Tr, Ti, xl, t, tw);
  float2 hx = h1[cx & 255];
#pragma unroll
  for (int j=0;j<16;j++){
    float2 r = cmul(v[j], cmul(h1[t + 16*j], hx));
    stout(outp, ib + ((t+16*j)<<8) + cx, r);
  }
}

template<int H>
static void run_new(const void* amp, const void* phase,
                    const void* df, const void* cs, const void* am, const void* aa,
                    const void* sm, const void* spos, const void* sidx, int B,
                    void* state, __half2* ttab, int use_tt,
                    void* dout, hipStream_t stream){
  char* dob = (char*)dout;
  float2* probe = (float2*)dob;
  float2* ptmp  = (float2*)(dob + 524288);
  probe_rowsF<<<16, 256, 0, stream>>>(df, cs, am, aa, sm, amp, ptmp);
  probe_colsF<<<16, 256, 0, stream>>>(ptmp, probe, sm, amp);
  if (use_tt) build_ttabF<<<8192, 256, 0, stream>>>(amp, phase, ttab);
  dim3 grid(16, B);
  row_passT<H><<<grid, 256, 0, stream>>>(amp, phase, spos, sidx, state, probe, ttab, 0, 1, use_tt);
  col_passT<H><<<grid, 256, 0, stream>>>(state);
  for (int s = 1; s < 7; s++){
    row_passT<H><<<grid, 256, 0, stream>>>(amp, phase, spos, sidx, state, probe, ttab, s, 0, use_tt);
    col_passT<H><<<grid, 256, 0, stream>>>(state);
  }
  row_passT<H><<<grid, 256, 0, stream>>>(amp, phase, spos, sidx, state, probe, ttab, 7, 0, use_tt);
  col_finT<H><<<grid, 256, 0, stream>>>(state, dout);
}

extern "C" void kernel_launch(void* const* d_in, const int* in_sizes, int n_in,
                              void* d_out, int out_size, void* d_ws, size_t ws_size,
                              hipStream_t stream) {
  const void* amp   = d_in[0];
  const void* phase = d_in[1];
  const void* df    = d_in[2];
  const void* cs    = d_in[3];
  const void* am    = d_in[4];
  const void* aa    = d_in[5];
  const void* sm    = d_in[6];
  const void* spos  = d_in[7];
  const void* sidx  = d_in[8];
  int B = in_sizes[8];
  (void)out_size; (void)n_in;

  size_t stateH = (size_t)B * 65536 * 4;            // fp16 state [B,256,256] c32 (half2)
  const size_t ttabB = (size_t)8 * 1024 * 1024 * 4; // 32 MB fp16 transmission table
  if (ws_size >= stateH + ttabB){
    void*    state = d_ws;
    __half2* ttab  = (__half2*)((char*)d_ws + stateH);
    run_new<1>(amp, phase, df, cs, am, aa, sm, spos, sidx, B,
               state, ttab, 1, d_out, stream);
  } else if (ws_size >= stateH){
    run_new<1>(amp, phase, df, cs, am, aa, sm, spos, sidx, B,
               d_ws, (__half2*)d_ws, 0, d_out, stream);
  } else {
    // no workspace: fp16 state lives in d_out itself (256KB/slot), tables inline
    run_new<1>(amp, phase, df, cs, am, aa, sm, spos, sidx, B,
               d_out, (__half2*)d_out, 0, d_out, stream);
  }
}